// Round 7
// baseline (364.947 us; speedup 1.0000x reference)
//
#include <hip/hip_runtime.h>

#define SEQ 2048
#define EMBED 1024
#define DHEAD 64

typedef _Float16 h8 __attribute__((ext_vector_type(8)));
typedef _Float16 h4 __attribute__((ext_vector_type(4)));
typedef float f4 __attribute__((ext_vector_type(4)));
typedef unsigned int u32;

// async global->LDS 16B copy. LDS dest is wave-uniform base + lane*16.
__device__ __forceinline__ void gload_lds16(const void* g, void* l) {
    __builtin_amdgcn_global_load_lds(
        (const __attribute__((address_space(1))) u32*)g,
        (__attribute__((address_space(3))) u32*)l, 16, 0, 0);
}

__device__ __forceinline__ h8 cvt8(f4 a, f4 b) {
    return (h8){ (_Float16)a[0], (_Float16)a[1], (_Float16)a[2], (_Float16)a[3],
                 (_Float16)b[0], (_Float16)b[1], (_Float16)b[2], (_Float16)b[3] };
}

// ---------------- weights-only fp32 -> f16 pass (Wq pre-scaled by 0.125*log2(e)) ----------------
// Activations (q/k/v) are now converted INSIDE proj_qkv's staging (saves a 168 MB round trip).
__global__ __launch_bounds__(256) void cvt_w(
    const float* __restrict__ wq, const float* __restrict__ wk,
    const float* __restrict__ wv, const float* __restrict__ wo,
    _Float16* __restrict__ wq16, _Float16* __restrict__ wk16,
    _Float16* __restrict__ wv16, _Float16* __restrict__ wo16)
{
    int bid = blockIdx.x;
    int seg = bid >> 10;
    size_t base = (size_t)(bid & 1023) * 1024 + threadIdx.x * 4;
    const float* src = seg == 0 ? wq : seg == 1 ? wk : seg == 2 ? wv : wo;
    _Float16* dst = seg == 0 ? wq16 : seg == 1 ? wk16 : seg == 2 ? wv16 : wo16;
    float scale = (seg == 0) ? 0.18033688011112042f : 1.0f;  // 0.125 * log2(e)
    float4 x = *(const float4*)(src + base);
    h4 y = { (_Float16)(x.x * scale), (_Float16)(x.y * scale),
             (_Float16)(x.z * scale), (_Float16)(x.w * scale) };
    *(h4*)(dst + base) = y;
}

// ---------------- f16 GEMM core v4: C[128x128] = A * W^T, K=1024, BK=32 ----------------
// template<A32,B32>: an fp32-side is staged global->reg->cvt->ds_write_b128 into the
// SAME row-major [128][32] LDS layout the f16 gload_lds path produces (dest tid*16B),
// fusing the f32->f16 conversion into the GEMM. f16 sides keep gload_lds.
// Verified single-buffer 2-barrier structure (__syncthreads orders vmcnt+lgkm).
template <bool A32, bool B32>
__device__ __forceinline__ void gemm_core_t(const void* Ap, const void* Wp,
                                            int m0, int n0, int tid,
                                            _Float16* As, _Float16* Bs, f4 acc[4][4])
{
    const int lane = tid & 63, wave = tid >> 6;
    const int t16 = lane & 15, quad = lane >> 4;
    const int wm = (wave >> 1) * 64, wn = (wave & 1) * 64;
    const int r0 = tid >> 2;           // row 0..63 (segment 2 adds +64)
    const int c0 = (tid & 3) * 8;      // col in elements (8-wide)

    for (int k0 = 0; k0 < 1024; k0 += 32) {
        __syncthreads();               // previous compute done; buffer free
        f4 xa0, xa1, xa2, xa3, xb0, xb1, xb2, xb3;
        if constexpr (A32) {           // issue fp32 A loads early (latency overlaps B staging)
            const float* ga = (const float*)Ap + (size_t)(m0 + r0) * 1024 + c0 + k0;
            xa0 = *(const f4*)ga;       xa1 = *(const f4*)(ga + 4);
            xa2 = *(const f4*)(ga + 65536); xa3 = *(const f4*)(ga + 65536 + 4);
        }
        if constexpr (B32) {
            const float* gb = (const float*)Wp + (size_t)(n0 + r0) * 1024 + c0 + k0;
            xb0 = *(const f4*)gb;       xb1 = *(const f4*)(gb + 4);
            xb2 = *(const f4*)(gb + 65536); xb3 = *(const f4*)(gb + 65536 + 4);
        }
        if constexpr (!A32) {
            const _Float16* ga = (const _Float16*)Ap + (size_t)(m0 + r0) * 1024 + c0 + k0;
            gload_lds16(ga, As + wave * 512);
            gload_lds16(ga + (size_t)64 * 1024, As + 2048 + wave * 512);
        }
        if constexpr (!B32) {
            const _Float16* gb = (const _Float16*)Wp + (size_t)(n0 + r0) * 1024 + c0 + k0;
            gload_lds16(gb, Bs + wave * 512);
            gload_lds16(gb + (size_t)64 * 1024, Bs + 2048 + wave * 512);
        }
        if constexpr (A32) {           // cvt + write (compiler inserts vmcnt before use)
            *(h8*)(As + tid * 8) = cvt8(xa0, xa1);
            *(h8*)(As + 2048 + tid * 8) = cvt8(xa2, xa3);
        }
        if constexpr (B32) {
            *(h8*)(Bs + tid * 8) = cvt8(xb0, xb1);
            *(h8*)(Bs + 2048 + tid * 8) = cvt8(xb2, xb3);
        }
        __syncthreads();               // drains vmcnt (gload_lds) + lgkm (ds_write)
        h8 af[4], bf[4];
#pragma unroll
        for (int i = 0; i < 4; ++i)
            af[i] = *(const h8*)(As + (wm + i * 16 + t16) * 32 + quad * 8);
#pragma unroll
        for (int j = 0; j < 4; ++j)
            bf[j] = *(const h8*)(Bs + (wn + j * 16 + t16) * 32 + quad * 8);
#pragma unroll
        for (int i = 0; i < 4; ++i)
#pragma unroll
            for (int j = 0; j < 4; ++j)
                acc[i][j] = __builtin_amdgcn_mfma_f32_16x16x32_f16(af[i], bf[j], acc[i][j], 0, 0, 0);
    }
}

// ---------------- fused QKV projection (reads fp32 activations directly) ----------------
// V is stored FRAGMENT-MAJOR for attn3's 16x16x16 PV path:
//   chunk c = jt*8 + dt*2 + j4p (1024 B each), within chunk: lane(quadv,t16v)*16B
//   holds V^T[dt*16+t16v][jt*64 + (j4p*2+j4lo)*16 + quadv*4 + reg] at byte j4lo*8+reg*2.
__global__ __launch_bounds__(256) void proj_qkv(
    const float* __restrict__ qf, const float* __restrict__ kf, const float* __restrict__ vf,
    const _Float16* __restrict__ Wq, const _Float16* __restrict__ Wk, const _Float16* __restrict__ Wv,
    _Float16* __restrict__ Qh, _Float16* __restrict__ Kh, _Float16* __restrict__ Vt)
{
    __shared__ _Float16 As[4096], Bs[4096];
    const int tid = threadIdx.x;
    const int z = blockIdx.z;
    int m0, n0;
    f4 acc[4][4];
    const f4 z4 = {0.f, 0.f, 0.f, 0.f};
#pragma unroll
    for (int i = 0; i < 4; ++i)
#pragma unroll
        for (int j = 0; j < 4; ++j) acc[i][j] = z4;

    if (z == 2) {
        m0 = blockIdx.y * 128; n0 = blockIdx.x * 128;
        gemm_core_t<false, true>(Wv, vf, m0, n0, tid, As, Bs, acc);   // A=Wv f16, B=value fp32
    } else if (z == 0) {
        m0 = blockIdx.x * 128; n0 = blockIdx.y * 128;
        gemm_core_t<true, false>(qf, Wq, m0, n0, tid, As, Bs, acc);   // A=query fp32, B=Wq f16
    } else {
        m0 = blockIdx.x * 128; n0 = blockIdx.y * 128;
        gemm_core_t<true, false>(kf, Wk, m0, n0, tid, As, Bs, acc);
    }

    const int lane = tid & 63, wave = tid >> 6;
    const int t16 = lane & 15, quad = lane >> 4;
    const int wm = (wave >> 1) * 64, wn = (wave & 1) * 64;
#pragma unroll
    for (int i = 0; i < 4; ++i)
#pragma unroll
        for (int j = 0; j < 4; ++j)
#pragma unroll
            for (int reg = 0; reg < 4; ++reg) {
                int gm = m0 + wm + i * 16 + quad * 4 + reg;
                int gn = n0 + wn + j * 16 + t16;
                float vv = acc[i][j][reg];
                if (z < 2) {
                    int b = gm >> 11, s = gm & 2047, h = gn >> 6, dd = gn & 63;
                    _Float16* dst = (z == 0) ? Qh : Kh;
                    dst[(((size_t)(b * 16 + h) * SEQ) + s) * DHEAD + dd] = (_Float16)vv;
                } else {
                    // gm = global d (h*64+dd), gn = global (b,s)
                    int h = gm >> 6, dd = gm & 63, b = gn >> 11, s = gn & 2047;
                    int jt = s >> 6, ks = s & 63;
                    int j4 = ks >> 4, quadv = (ks >> 2) & 3, regv = ks & 3;
                    int dt = dd >> 4, t16v = dd & 15;
                    size_t off = (size_t)(b * 16 + h) * (SEQ * DHEAD)
                               + (size_t)(jt * 8 + dt * 2 + (j4 >> 1)) * 512
                               + (quadv * 16 + t16v) * 8 + (j4 & 1) * 4 + regv;
                    Vt[off] = (_Float16)vv;
                }
            }
}

// ---------------- causal flash attention v4 (verified 83us; unchanged) ----------------
// block = (b,h) x 128 q-rows; wave w owns q [q0+w*32, +32) as 2 q-blocks of 16.
// S^T = K.Q^T via 16x16x32 (C layout: row=quad*4+reg, col=t16=q) -> softmax in-lane.
// PV via 16x16x16: its B-operand layout (k=quad*4+j, col=t16) IS the S^T C layout,
// so P^T feeds PV directly from registers -- NO LDS exchange. V staged fragment-major.
// LDS: Kbuf+Vbuf only = 32 KB; epilogue reuses dead Kbuf (XOR-swizzled).
// Both q-blocks processed in parallel (independent chains -> ILP). Defer-max kept.
__global__ __launch_bounds__(256) void attn3(
    const _Float16* __restrict__ Qh, const _Float16* __restrict__ Kh,
    const _Float16* __restrict__ Vt, _Float16* __restrict__ Ob)
{
    __shared__ _Float16 Kbuf[2][8][512];   // [buf][(kv16grp)*2+kc][lane*8]  (16 KB)
    __shared__ _Float16 Vbuf[2][8][512];   // [buf][dt*2+j4p][lane*8]        (16 KB)

    const int tid = threadIdx.x;
    const int lane = tid & 63, wave = tid >> 6;
    const int t16 = lane & 15, quad = lane >> 4;
    const int bh = blockIdx.x;
    const int b = bh >> 4, h = bh & 15;
    const int qb = (gridDim.y - 1) - blockIdx.y;   // heavy blocks first
    const int q0 = qb * 128;
    const int nqt = qb * 2 + 2;

    const _Float16* Qp = Qh + (size_t)bh * SEQ * DHEAD;
    const _Float16* Kp = Kh + (size_t)bh * SEQ * DHEAD;
    const _Float16* Vp = Vt + (size_t)bh * SEQ * DHEAD;

    const int qlo[2] = { q0 + wave * 32, q0 + wave * 32 + 16 };
    const int last0 = (qlo[0] + 15) >> 6;   // == (qlo[1]+15)>>6 for this geometry

    // Q fragments (B-operand of 16x16x32: lane holds Q[q=t16][d=kc*32+quad*8+j])
    h8 qf[2][2];
#pragma unroll
    for (int qb2 = 0; qb2 < 2; ++qb2)
#pragma unroll
        for (int kc = 0; kc < 2; ++kc)
            qf[qb2][kc] = *(const h8*)(Qp + (size_t)(qlo[qb2] + t16) * 64 + kc * 32 + quad * 8);

    // per-lane staging bases
    const _Float16* Kl = Kp + t16 * 64 + quad * 8;   // K row-major [s][d]
    const _Float16* Vl = Vp + lane * 8;              // V fragment-major chunks

#define STAGE(jt_, bufi)                                                                  \
    do {                                                                                  \
        if (wave < 2) {                                                                   \
            _Pragma("unroll")                                                             \
            for (int i_ = 0; i_ < 4; ++i_) {                                              \
                int g_ = wave * 4 + i_;                                                   \
                gload_lds16(Kl + (jt_) * 4096 + (g_ >> 1) * 1024 + (g_ & 1) * 32,         \
                            &Kbuf[bufi][g_][0]);                                          \
            }                                                                             \
        } else {                                                                          \
            _Pragma("unroll")                                                             \
            for (int i_ = 0; i_ < 4; ++i_) {                                              \
                int g_ = (wave - 2) * 4 + i_;                                             \
                gload_lds16(Vl + ((jt_) * 8 + g_) * 512, &Vbuf[bufi][g_][0]);             \
            }                                                                             \
        }                                                                                 \
    } while (0)

    STAGE(0, 0);
    __syncthreads();

    float mv[2] = {-1e30f, -1e30f};
    float lv[2] = {0.f, 0.f};
    f4 o_acc[2][4];
    const f4 z4 = {0.f, 0.f, 0.f, 0.f};
#pragma unroll
    for (int qb2 = 0; qb2 < 2; ++qb2)
#pragma unroll
        for (int dt = 0; dt < 4; ++dt) o_acc[qb2][dt] = z4;

    for (int jt = 0; jt < nqt; ++jt) {
        const int buf = jt & 1;
        if (jt + 1 < nqt) STAGE(jt + 1, buf ^ 1);

        if (jt <= last0) {
            // S^T = K.Q^T  (rows k = jt*64 + j4*16 + quad*4 + reg, col q = t16)
            f4 s0[4], s1[4];
#pragma unroll
            for (int j4 = 0; j4 < 4; ++j4) {
                h8 kfa = *(const h8*)(&Kbuf[buf][j4 * 2 + 0][lane * 8]);
                h8 kfb = *(const h8*)(&Kbuf[buf][j4 * 2 + 1][lane * 8]);
                s1[j4] = __builtin_amdgcn_mfma_f32_16x16x32_f16(kfa, qf[1][0], z4, 0, 0, 0);
                s1[j4] = __builtin_amdgcn_mfma_f32_16x16x32_f16(kfb, qf[1][1], s1[j4], 0, 0, 0);
                s0[j4] = __builtin_amdgcn_mfma_f32_16x16x32_f16(kfa, qf[0][0], z4, 0, 0, 0);
                s0[j4] = __builtin_amdgcn_mfma_f32_16x16x32_f16(kfb, qf[0][1], s0[j4], 0, 0, 0);
            }

            // per-q-block online softmax (defer-max); P^T stays in registers as x16 B-frags
            h4 pf0[4], pf1[4];
            auto softmax_frag = [&](f4* s, int qb2, h4* pf) {
                const int myq = qlo[qb2] + t16;
                if ((jt << 6) + 63 > qlo[qb2]) {   // tile touches diagonal for this q-block
#pragma unroll
                    for (int j4 = 0; j4 < 4; ++j4)
#pragma unroll
                        for (int reg = 0; reg < 4; ++reg) {
                            int kk = (jt << 6) + j4 * 16 + quad * 4 + reg;
                            if (kk > myq) s[j4][reg] = -1e30f;
                        }
                }
                float mr = s[0][0];
#pragma unroll
                for (int j4 = 0; j4 < 4; ++j4)
#pragma unroll
                    for (int reg = 0; reg < 4; ++reg) mr = fmaxf(mr, s[j4][reg]);
                mr = fmaxf(mr, __shfl_xor(mr, 16, 64));
                mr = fmaxf(mr, __shfl_xor(mr, 32, 64));
                float mn = mv[qb2];
                if (__any(mr > mn + 8.0f)) {       // T13: rescale only on real max growth
                    mn = fmaxf(mn, mr);
                    float al = __builtin_amdgcn_exp2f(mv[qb2] - mn);
                    mv[qb2] = mn;
                    lv[qb2] *= al;
#pragma unroll
                    for (int dt = 0; dt < 4; ++dt)
#pragma unroll
                        for (int reg = 0; reg < 4; ++reg) o_acc[qb2][dt][reg] *= al;
                }
                float rs = 0.f;
#pragma unroll
                for (int j4 = 0; j4 < 4; ++j4) {
#pragma unroll
                    for (int reg = 0; reg < 4; ++reg) {
                        float p = __builtin_amdgcn_exp2f(s[j4][reg] - mn);
                        s[j4][reg] = p;
                        rs += p;
                    }
                    pf[j4] = (h4){ (_Float16)s[j4][0], (_Float16)s[j4][1],
                                   (_Float16)s[j4][2], (_Float16)s[j4][3] };
                }
                rs += __shfl_xor(rs, 16, 64);
                rs += __shfl_xor(rs, 32, 64);
                lv[qb2] += rs;
            };
            softmax_frag(s0, 0, pf0);
            softmax_frag(s1, 1, pf1);

            // PV: O^T += V^T.P^T via 16x16x16 (B-frag == S^T C-layout, in-register)
#pragma unroll
            for (int dt = 0; dt < 4; ++dt) {
#pragma unroll
                for (int j4p = 0; j4p < 2; ++j4p) {
                    h8 v2 = *(const h8*)(&Vbuf[buf][dt * 2 + j4p][lane * 8]);
                    h4 vlo = __builtin_shufflevector(v2, v2, 0, 1, 2, 3);
                    h4 vhi = __builtin_shufflevector(v2, v2, 4, 5, 6, 7);
                    o_acc[0][dt] = __builtin_amdgcn_mfma_f32_16x16x16f16(vlo, pf0[j4p * 2 + 0], o_acc[0][dt], 0, 0, 0);
                    o_acc[0][dt] = __builtin_amdgcn_mfma_f32_16x16x16f16(vhi, pf0[j4p * 2 + 1], o_acc[0][dt], 0, 0, 0);
                    o_acc[1][dt] = __builtin_amdgcn_mfma_f32_16x16x16f16(vlo, pf1[j4p * 2 + 0], o_acc[1][dt], 0, 0, 0);
                    o_acc[1][dt] = __builtin_amdgcn_mfma_f32_16x16x16f16(vhi, pf1[j4p * 2 + 1], o_acc[1][dt], 0, 0, 0);
                }
            }
        }
        __syncthreads();
    }

    // epilogue: O^T -> (same-wave LDS transpose in dead Kbuf, XOR-swizzled) -> f16 store
    _Float16* ep = ((_Float16*)Kbuf) + wave * 1024;   // [q=16][d=64] per wave
    const int swz = (t16 & 7) << 3;                   // toggles half-index bits 3..5
#pragma unroll
    for (int qb2 = 0; qb2 < 2; ++qb2) {
        float inv = __builtin_amdgcn_rcpf(lv[qb2]);
#pragma unroll
        for (int dt = 0; dt < 4; ++dt) {
            h4 ov = { (_Float16)(o_acc[qb2][dt][0] * inv), (_Float16)(o_acc[qb2][dt][1] * inv),
                      (_Float16)(o_acc[qb2][dt][2] * inv), (_Float16)(o_acc[qb2][dt][3] * inv) };
            *(h4*)(ep + t16 * 64 + ((dt * 16 + quad * 4) ^ swz)) = ov;
        }
        h8 r0 = *(const h8*)(ep + t16 * 64 + ((quad * 8) ^ swz));
        h8 r1 = *(const h8*)(ep + t16 * 64 + ((32 + quad * 8) ^ swz));
        int s = qlo[qb2] + t16;
        _Float16* og = Ob + ((size_t)(b * SEQ + s)) * EMBED + h * DHEAD;
        *(h8*)(og + quad * 8) = r0;
        *(h8*)(og + 32 + quad * 8) = r1;
    }
#undef STAGE
}

// ---------------- output projection: out = Ob(f16) * Wo^T, fp32 out ----------------
__global__ __launch_bounds__(256) void proj_out(
    const _Float16* __restrict__ A, const _Float16* __restrict__ Wo, float* __restrict__ out)
{
    __shared__ _Float16 As[4096], Bs[4096];
    const int tid = threadIdx.x;
    const int m0 = blockIdx.x * 128, n0 = blockIdx.y * 128;
    f4 acc[4][4];
    const f4 z4 = {0.f, 0.f, 0.f, 0.f};
#pragma unroll
    for (int i = 0; i < 4; ++i)
#pragma unroll
        for (int j = 0; j < 4; ++j) acc[i][j] = z4;

    gemm_core_t<false, false>(A, Wo, m0, n0, tid, As, Bs, acc);

    const int lane = tid & 63, wave = tid >> 6;
    const int t16 = lane & 15, quad = lane >> 4;
    const int wm = (wave >> 1) * 64, wn = (wave & 1) * 64;
#pragma unroll
    for (int i = 0; i < 4; ++i)
#pragma unroll
        for (int j = 0; j < 4; ++j)
#pragma unroll
            for (int reg = 0; reg < 4; ++reg) {
                int gm = m0 + wm + i * 16 + quad * 4 + reg;
                int gn = n0 + wn + j * 16 + t16;
                out[(size_t)gm * EMBED + gn] = acc[i][j][reg];
            }
}

extern "C" void kernel_launch(void* const* d_in, const int* in_sizes, int n_in,
                              void* d_out, int out_size, void* d_ws, size_t ws_size,
                              hipStream_t stream) {
    const float* key   = (const float*)d_in[0];
    const float* query = (const float*)d_in[1];
    const float* value = (const float*)d_in[2];
    // d_in[3] = mask: causal tril, hardcoded
    const float* Wq = (const float*)d_in[4];
    const float* Wk = (const float*)d_in[5];
    const float* Wv = (const float*)d_in[6];
    const float* Wo = (const float*)d_in[7];

    char* ws = (char*)d_ws;
    _Float16* Ob   = (_Float16*)(ws);                // 16 MiB
    _Float16* Wq16 = (_Float16*)(ws + (16u << 20));  // 2 MiB each
    _Float16* Wk16 = (_Float16*)(ws + (18u << 20));
    _Float16* Wv16 = (_Float16*)(ws + (20u << 20));
    _Float16* Wo16 = (_Float16*)(ws + (22u << 20));
    _Float16* Qh   = (_Float16*)(ws + (24u << 20));  // 16 MiB [B,H,S,d]
    _Float16* Kh   = (_Float16*)(ws + (40u << 20));  // 16 MiB [B,H,S,d]
    _Float16* Vt   = (_Float16*)(ws + (56u << 20));  // 16 MiB, V fragment-major (see proj_qkv)

    dim3 blk(256);
    cvt_w<<<dim3(4096), blk, 0, stream>>>(Wq, Wk, Wv, Wo, Wq16, Wk16, Wv16, Wo16);
    proj_qkv<<<dim3(64, 8, 3), blk, 0, stream>>>(query, key, value, Wq16, Wk16, Wv16, Qh, Kh, Vt);
    attn3<<<dim3(64, 16), blk, 0, stream>>>(Qh, Kh, Vt, Ob);
    proj_out<<<dim3(64, 8), blk, 0, stream>>>(Ob, Wo16, (float*)d_out);
}

// Round 8
// 362.709 us; speedup vs baseline: 1.0062x; 1.0062x over previous
//
#include <hip/hip_runtime.h>

#define SEQ 2048
#define EMBED 1024
#define DHEAD 64

typedef _Float16 h8 __attribute__((ext_vector_type(8)));
typedef _Float16 h4 __attribute__((ext_vector_type(4)));
typedef float f4 __attribute__((ext_vector_type(4)));
typedef unsigned int u32;

// async global->LDS 16B copy. LDS dest is wave-uniform base + lane*16.
__device__ __forceinline__ void gload_lds16(const void* g, void* l) {
    __builtin_amdgcn_global_load_lds(
        (const __attribute__((address_space(1))) u32*)g,
        (__attribute__((address_space(3))) u32*)l, 16, 0, 0);
}

__device__ __forceinline__ h8 cvt8(f4 a, f4 b) {
    return (h8){ (_Float16)a[0], (_Float16)a[1], (_Float16)a[2], (_Float16)a[3],
                 (_Float16)b[0], (_Float16)b[1], (_Float16)b[2], (_Float16)b[3] };
}

// ---------------- weights-only fp32 -> f16 pass (Wq pre-scaled by 0.125*log2(e)) ----------------
__global__ __launch_bounds__(256) void cvt_w(
    const float* __restrict__ wq, const float* __restrict__ wk,
    const float* __restrict__ wv, const float* __restrict__ wo,
    _Float16* __restrict__ wq16, _Float16* __restrict__ wk16,
    _Float16* __restrict__ wv16, _Float16* __restrict__ wo16)
{
    int bid = blockIdx.x;
    int seg = bid >> 10;
    size_t base = (size_t)(bid & 1023) * 1024 + threadIdx.x * 4;
    const float* src = seg == 0 ? wq : seg == 1 ? wk : seg == 2 ? wv : wo;
    _Float16* dst = seg == 0 ? wq16 : seg == 1 ? wk16 : seg == 2 ? wv16 : wo16;
    float scale = (seg == 0) ? 0.18033688011112042f : 1.0f;  // 0.125 * log2(e)
    float4 x = *(const float4*)(src + base);
    h4 y = { (_Float16)(x.x * scale), (_Float16)(x.y * scale),
             (_Float16)(x.z * scale), (_Float16)(x.w * scale) };
    *(h4*)(dst + base) = y;
}

// ---------------- f16 GEMM core v5: C[128x128] = A * W^T, K=1024, BK=32 ----------------
// T14 async-STAGE + double buffer, ONE barrier per k-step:
//   iter k: [issue tile k+1 loads] -> [compute tile k] -> [cvt+ds_write fp32 side k+1]
//           -> __syncthreads (drains vmcnt+lgkm; latency was hidden under compute).
// fp32 sides (A32/B32) are reg-staged global->reg->cvt->ds_write into the SAME
// row-major [128][32] layout the f16 gload_lds path produces. R7's version exposed
// the f32 chain between two barriers every step (proj_qkv 83->128us); this hides it.
template <bool A32, bool B32>
__device__ __forceinline__ void gemm_core_t(const void* Ap, const void* Wp,
                                            int m0, int n0, int tid,
                                            _Float16* As, _Float16* Bs, f4 acc[4][4])
{
    const int lane = tid & 63, wave = tid >> 6;
    const int t16 = lane & 15, quad = lane >> 4;
    const int wm = (wave >> 1) * 64, wn = (wave & 1) * 64;
    const int r0 = tid >> 2;           // row 0..63 (second segment adds +64)
    const int c0 = (tid & 3) * 8;      // col in elements (8-wide)

    f4 xa0, xa1, xa2, xa3, xb0, xb1, xb2, xb3;

    auto loadA = [&](int k0, int bf) {
        if constexpr (A32) {
            const float* ga = (const float*)Ap + (size_t)(m0 + r0) * 1024 + c0 + k0;
            xa0 = *(const f4*)ga;           xa1 = *(const f4*)(ga + 4);
            xa2 = *(const f4*)(ga + 65536); xa3 = *(const f4*)(ga + 65536 + 4);
        } else {
            const _Float16* ga = (const _Float16*)Ap + (size_t)(m0 + r0) * 1024 + c0 + k0;
            gload_lds16(ga, As + bf * 4096 + wave * 512);
            gload_lds16(ga + (size_t)64 * 1024, As + bf * 4096 + 2048 + wave * 512);
        }
    };
    auto loadB = [&](int k0, int bf) {
        if constexpr (B32) {
            const float* gb = (const float*)Wp + (size_t)(n0 + r0) * 1024 + c0 + k0;
            xb0 = *(const f4*)gb;           xb1 = *(const f4*)(gb + 4);
            xb2 = *(const f4*)(gb + 65536); xb3 = *(const f4*)(gb + 65536 + 4);
        } else {
            const _Float16* gb = (const _Float16*)Wp + (size_t)(n0 + r0) * 1024 + c0 + k0;
            gload_lds16(gb, Bs + bf * 4096 + wave * 512);
            gload_lds16(gb + (size_t)64 * 1024, Bs + bf * 4096 + 2048 + wave * 512);
        }
    };
    auto writeA = [&](int bf) {
        if constexpr (A32) {
            *(h8*)(As + bf * 4096 + tid * 8) = cvt8(xa0, xa1);
            *(h8*)(As + bf * 4096 + 2048 + tid * 8) = cvt8(xa2, xa3);
        }
    };
    auto writeB = [&](int bf) {
        if constexpr (B32) {
            *(h8*)(Bs + bf * 4096 + tid * 8) = cvt8(xb0, xb1);
            *(h8*)(Bs + bf * 4096 + 2048 + tid * 8) = cvt8(xb2, xb3);
        }
    };

    // prologue: stage tile 0 into buf 0
    loadA(0, 0);
    loadB(0, 0);
    writeA(0);
    writeB(0);
    __syncthreads();   // drains gload_lds vmcnt + ds_write lgkm

    for (int k = 0; k < 32; ++k) {
        const int b = k & 1;
        // 1) issue next tile's loads FIRST (latency hides under this tile's compute)
        if (k < 31) {
            loadA((k + 1) * 32, b ^ 1);
            loadB((k + 1) * 32, b ^ 1);
        }
        // 2) compute tile k from buf b
        const _Float16* As_ = As + b * 4096;
        const _Float16* Bs_ = Bs + b * 4096;
        h8 af[4], bf4[4];
#pragma unroll
        for (int i = 0; i < 4; ++i)
            af[i] = *(const h8*)(As_ + (wm + i * 16 + t16) * 32 + quad * 8);
#pragma unroll
        for (int j = 0; j < 4; ++j)
            bf4[j] = *(const h8*)(Bs_ + (wn + j * 16 + t16) * 32 + quad * 8);
#pragma unroll
        for (int i = 0; i < 4; ++i)
#pragma unroll
            for (int j = 0; j < 4; ++j)
                acc[i][j] = __builtin_amdgcn_mfma_f32_16x16x32_f16(af[i], bf4[j], acc[i][j], 0, 0, 0);
        // 3) cvt + ds_write the fp32 side for tile k+1 (vmcnt wait lands here, post-compute)
        if (k < 31) {
            writeA(b ^ 1);
            writeB(b ^ 1);
        }
        // 4) single barrier: drains vmcnt (gload_lds k+1) + lgkm (ds_write k+1);
        //    orders all reads-of-buf-b before next iteration overwrites it.
        __syncthreads();
    }
}

// ---------------- fused QKV projection (reads fp32 activations directly) ----------------
// V is stored FRAGMENT-MAJOR for attn3's 16x16x16 PV path:
//   chunk c = jt*8 + dt*2 + j4p (1024 B each), within chunk: lane(quadv,t16v)*16B
//   holds V^T[dt*16+t16v][jt*64 + (j4p*2+j4lo)*16 + quadv*4 + reg] at byte j4lo*8+reg*2.
__global__ __launch_bounds__(256) void proj_qkv(
    const float* __restrict__ qf, const float* __restrict__ kf, const float* __restrict__ vf,
    const _Float16* __restrict__ Wq, const _Float16* __restrict__ Wk, const _Float16* __restrict__ Wv,
    _Float16* __restrict__ Qh, _Float16* __restrict__ Kh, _Float16* __restrict__ Vt)
{
    __shared__ _Float16 As[8192], Bs[8192];   // 2 bufs x [128][32]
    const int tid = threadIdx.x;
    const int z = blockIdx.z;
    int m0, n0;
    f4 acc[4][4];
    const f4 z4 = {0.f, 0.f, 0.f, 0.f};
#pragma unroll
    for (int i = 0; i < 4; ++i)
#pragma unroll
        for (int j = 0; j < 4; ++j) acc[i][j] = z4;

    if (z == 2) {
        m0 = blockIdx.y * 128; n0 = blockIdx.x * 128;
        gemm_core_t<false, true>(Wv, vf, m0, n0, tid, As, Bs, acc);   // A=Wv f16, B=value fp32
    } else if (z == 0) {
        m0 = blockIdx.x * 128; n0 = blockIdx.y * 128;
        gemm_core_t<true, false>(qf, Wq, m0, n0, tid, As, Bs, acc);   // A=query fp32, B=Wq f16
    } else {
        m0 = blockIdx.x * 128; n0 = blockIdx.y * 128;
        gemm_core_t<true, false>(kf, Wk, m0, n0, tid, As, Bs, acc);
    }

    const int lane = tid & 63, wave = tid >> 6;
    const int t16 = lane & 15, quad = lane >> 4;
    const int wm = (wave >> 1) * 64, wn = (wave & 1) * 64;
#pragma unroll
    for (int i = 0; i < 4; ++i)
#pragma unroll
        for (int j = 0; j < 4; ++j)
#pragma unroll
            for (int reg = 0; reg < 4; ++reg) {
                int gm = m0 + wm + i * 16 + quad * 4 + reg;
                int gn = n0 + wn + j * 16 + t16;
                float vv = acc[i][j][reg];
                if (z < 2) {
                    int b = gm >> 11, s = gm & 2047, h = gn >> 6, dd = gn & 63;
                    _Float16* dst = (z == 0) ? Qh : Kh;
                    dst[(((size_t)(b * 16 + h) * SEQ) + s) * DHEAD + dd] = (_Float16)vv;
                } else {
                    // gm = global d (h*64+dd), gn = global (b,s)
                    int h = gm >> 6, dd = gm & 63, b = gn >> 11, s = gn & 2047;
                    int jt = s >> 6, ks = s & 63;
                    int j4 = ks >> 4, quadv = (ks >> 2) & 3, regv = ks & 3;
                    int dt = dd >> 4, t16v = dd & 15;
                    size_t off = (size_t)(b * 16 + h) * (SEQ * DHEAD)
                               + (size_t)(jt * 8 + dt * 2 + (j4 >> 1)) * 512
                               + (quadv * 16 + t16v) * 8 + (j4 & 1) * 4 + regv;
                    Vt[off] = (_Float16)vv;
                }
            }
}

// ---------------- causal flash attention v4 (verified 83us; unchanged) ----------------
// block = (b,h) x 128 q-rows; wave w owns q [q0+w*32, +32) as 2 q-blocks of 16.
// S^T = K.Q^T via 16x16x32 (C layout: row=quad*4+reg, col=t16=q) -> softmax in-lane.
// PV via 16x16x16: its B-operand layout (k=quad*4+j, col=t16) IS the S^T C layout,
// so P^T feeds PV directly from registers -- NO LDS exchange. V staged fragment-major.
// LDS: Kbuf+Vbuf only = 32 KB; epilogue reuses dead Kbuf (XOR-swizzled).
// Both q-blocks processed in parallel (independent chains -> ILP). Defer-max kept.
__global__ __launch_bounds__(256) void attn3(
    const _Float16* __restrict__ Qh, const _Float16* __restrict__ Kh,
    const _Float16* __restrict__ Vt, _Float16* __restrict__ Ob)
{
    __shared__ _Float16 Kbuf[2][8][512];   // [buf][(kv16grp)*2+kc][lane*8]  (16 KB)
    __shared__ _Float16 Vbuf[2][8][512];   // [buf][dt*2+j4p][lane*8]        (16 KB)

    const int tid = threadIdx.x;
    const int lane = tid & 63, wave = tid >> 6;
    const int t16 = lane & 15, quad = lane >> 4;
    const int bh = blockIdx.x;
    const int b = bh >> 4, h = bh & 15;
    const int qb = (gridDim.y - 1) - blockIdx.y;   // heavy blocks first
    const int q0 = qb * 128;
    const int nqt = qb * 2 + 2;

    const _Float16* Qp = Qh + (size_t)bh * SEQ * DHEAD;
    const _Float16* Kp = Kh + (size_t)bh * SEQ * DHEAD;
    const _Float16* Vp = Vt + (size_t)bh * SEQ * DHEAD;

    const int qlo[2] = { q0 + wave * 32, q0 + wave * 32 + 16 };
    const int last0 = (qlo[0] + 15) >> 6;   // == (qlo[1]+15)>>6 for this geometry

    // Q fragments (B-operand of 16x16x32: lane holds Q[q=t16][d=kc*32+quad*8+j])
    h8 qf[2][2];
#pragma unroll
    for (int qb2 = 0; qb2 < 2; ++qb2)
#pragma unroll
        for (int kc = 0; kc < 2; ++kc)
            qf[qb2][kc] = *(const h8*)(Qp + (size_t)(qlo[qb2] + t16) * 64 + kc * 32 + quad * 8);

    // per-lane staging bases
    const _Float16* Kl = Kp + t16 * 64 + quad * 8;   // K row-major [s][d]
    const _Float16* Vl = Vp + lane * 8;              // V fragment-major chunks

#define STAGE(jt_, bufi)                                                                  \
    do {                                                                                  \
        if (wave < 2) {                                                                   \
            _Pragma("unroll")                                                             \
            for (int i_ = 0; i_ < 4; ++i_) {                                              \
                int g_ = wave * 4 + i_;                                                   \
                gload_lds16(Kl + (jt_) * 4096 + (g_ >> 1) * 1024 + (g_ & 1) * 32,         \
                            &Kbuf[bufi][g_][0]);                                          \
            }                                                                             \
        } else {                                                                          \
            _Pragma("unroll")                                                             \
            for (int i_ = 0; i_ < 4; ++i_) {                                              \
                int g_ = (wave - 2) * 4 + i_;                                             \
                gload_lds16(Vl + ((jt_) * 8 + g_) * 512, &Vbuf[bufi][g_][0]);             \
            }                                                                             \
        }                                                                                 \
    } while (0)

    STAGE(0, 0);
    __syncthreads();

    float mv[2] = {-1e30f, -1e30f};
    float lv[2] = {0.f, 0.f};
    f4 o_acc[2][4];
    const f4 z4 = {0.f, 0.f, 0.f, 0.f};
#pragma unroll
    for (int qb2 = 0; qb2 < 2; ++qb2)
#pragma unroll
        for (int dt = 0; dt < 4; ++dt) o_acc[qb2][dt] = z4;

    for (int jt = 0; jt < nqt; ++jt) {
        const int buf = jt & 1;
        if (jt + 1 < nqt) STAGE(jt + 1, buf ^ 1);

        if (jt <= last0) {
            // S^T = K.Q^T  (rows k = jt*64 + j4*16 + quad*4 + reg, col q = t16)
            f4 s0[4], s1[4];
#pragma unroll
            for (int j4 = 0; j4 < 4; ++j4) {
                h8 kfa = *(const h8*)(&Kbuf[buf][j4 * 2 + 0][lane * 8]);
                h8 kfb = *(const h8*)(&Kbuf[buf][j4 * 2 + 1][lane * 8]);
                s1[j4] = __builtin_amdgcn_mfma_f32_16x16x32_f16(kfa, qf[1][0], z4, 0, 0, 0);
                s1[j4] = __builtin_amdgcn_mfma_f32_16x16x32_f16(kfb, qf[1][1], s1[j4], 0, 0, 0);
                s0[j4] = __builtin_amdgcn_mfma_f32_16x16x32_f16(kfa, qf[0][0], z4, 0, 0, 0);
                s0[j4] = __builtin_amdgcn_mfma_f32_16x16x32_f16(kfb, qf[0][1], s0[j4], 0, 0, 0);
            }

            // per-q-block online softmax (defer-max); P^T stays in registers as x16 B-frags
            h4 pf0[4], pf1[4];
            auto softmax_frag = [&](f4* s, int qb2, h4* pf) {
                const int myq = qlo[qb2] + t16;
                if ((jt << 6) + 63 > qlo[qb2]) {   // tile touches diagonal for this q-block
#pragma unroll
                    for (int j4 = 0; j4 < 4; ++j4)
#pragma unroll
                        for (int reg = 0; reg < 4; ++reg) {
                            int kk = (jt << 6) + j4 * 16 + quad * 4 + reg;
                            if (kk > myq) s[j4][reg] = -1e30f;
                        }
                }
                float mr = s[0][0];
#pragma unroll
                for (int j4 = 0; j4 < 4; ++j4)
#pragma unroll
                    for (int reg = 0; reg < 4; ++reg) mr = fmaxf(mr, s[j4][reg]);
                mr = fmaxf(mr, __shfl_xor(mr, 16, 64));
                mr = fmaxf(mr, __shfl_xor(mr, 32, 64));
                float mn = mv[qb2];
                if (__any(mr > mn + 8.0f)) {       // T13: rescale only on real max growth
                    mn = fmaxf(mn, mr);
                    float al = __builtin_amdgcn_exp2f(mv[qb2] - mn);
                    mv[qb2] = mn;
                    lv[qb2] *= al;
#pragma unroll
                    for (int dt = 0; dt < 4; ++dt)
#pragma unroll
                        for (int reg = 0; reg < 4; ++reg) o_acc[qb2][dt][reg] *= al;
                }
                float rs = 0.f;
#pragma unroll
                for (int j4 = 0; j4 < 4; ++j4) {
#pragma unroll
                    for (int reg = 0; reg < 4; ++reg) {
                        float p = __builtin_amdgcn_exp2f(s[j4][reg] - mn);
                        s[j4][reg] = p;
                        rs += p;
                    }
                    pf[j4] = (h4){ (_Float16)s[j4][0], (_Float16)s[j4][1],
                                   (_Float16)s[j4][2], (_Float16)s[j4][3] };
                }
                rs += __shfl_xor(rs, 16, 64);
                rs += __shfl_xor(rs, 32, 64);
                lv[qb2] += rs;
            };
            softmax_frag(s0, 0, pf0);
            softmax_frag(s1, 1, pf1);

            // PV: O^T += V^T.P^T via 16x16x16 (B-frag == S^T C-layout, in-register)
#pragma unroll
            for (int dt = 0; dt < 4; ++dt) {
#pragma unroll
                for (int j4p = 0; j4p < 2; ++j4p) {
                    h8 v2 = *(const h8*)(&Vbuf[buf][dt * 2 + j4p][lane * 8]);
                    h4 vlo = __builtin_shufflevector(v2, v2, 0, 1, 2, 3);
                    h4 vhi = __builtin_shufflevector(v2, v2, 4, 5, 6, 7);
                    o_acc[0][dt] = __builtin_amdgcn_mfma_f32_16x16x16f16(vlo, pf0[j4p * 2 + 0], o_acc[0][dt], 0, 0, 0);
                    o_acc[0][dt] = __builtin_amdgcn_mfma_f32_16x16x16f16(vhi, pf0[j4p * 2 + 1], o_acc[0][dt], 0, 0, 0);
                    o_acc[1][dt] = __builtin_amdgcn_mfma_f32_16x16x16f16(vlo, pf1[j4p * 2 + 0], o_acc[1][dt], 0, 0, 0);
                    o_acc[1][dt] = __builtin_amdgcn_mfma_f32_16x16x16f16(vhi, pf1[j4p * 2 + 1], o_acc[1][dt], 0, 0, 0);
                }
            }
        }
        __syncthreads();
    }

    // epilogue: O^T -> (same-wave LDS transpose in dead Kbuf, XOR-swizzled) -> f16 store
    _Float16* ep = ((_Float16*)Kbuf) + wave * 1024;   // [q=16][d=64] per wave
    const int swz = (t16 & 7) << 3;                   // toggles half-index bits 3..5
#pragma unroll
    for (int qb2 = 0; qb2 < 2; ++qb2) {
        float inv = __builtin_amdgcn_rcpf(lv[qb2]);
#pragma unroll
        for (int dt = 0; dt < 4; ++dt) {
            h4 ov = { (_Float16)(o_acc[qb2][dt][0] * inv), (_Float16)(o_acc[qb2][dt][1] * inv),
                      (_Float16)(o_acc[qb2][dt][2] * inv), (_Float16)(o_acc[qb2][dt][3] * inv) };
            *(h4*)(ep + t16 * 64 + ((dt * 16 + quad * 4) ^ swz)) = ov;
        }
        h8 r0 = *(const h8*)(ep + t16 * 64 + ((quad * 8) ^ swz));
        h8 r1 = *(const h8*)(ep + t16 * 64 + ((32 + quad * 8) ^ swz));
        int s = qlo[qb2] + t16;
        _Float16* og = Ob + ((size_t)(b * SEQ + s)) * EMBED + h * DHEAD;
        *(h8*)(og + quad * 8) = r0;
        *(h8*)(og + 32 + quad * 8) = r1;
    }
#undef STAGE
}

// ---------------- output projection: out = Ob(f16) * Wo^T, fp32 out ----------------
__global__ __launch_bounds__(256) void proj_out(
    const _Float16* __restrict__ A, const _Float16* __restrict__ Wo, float* __restrict__ out)
{
    __shared__ _Float16 As[8192], Bs[8192];   // 2 bufs x [128][32]
    const int tid = threadIdx.x;
    const int m0 = blockIdx.x * 128, n0 = blockIdx.y * 128;
    f4 acc[4][4];
    const f4 z4 = {0.f, 0.f, 0.f, 0.f};
#pragma unroll
    for (int i = 0; i < 4; ++i)
#pragma unroll
        for (int j = 0; j < 4; ++j) acc[i][j] = z4;

    gemm_core_t<false, false>(A, Wo, m0, n0, tid, As, Bs, acc);

    const int lane = tid & 63, wave = tid >> 6;
    const int t16 = lane & 15, quad = lane >> 4;
    const int wm = (wave >> 1) * 64, wn = (wave & 1) * 64;
#pragma unroll
    for (int i = 0; i < 4; ++i)
#pragma unroll
        for (int j = 0; j < 4; ++j)
#pragma unroll
            for (int reg = 0; reg < 4; ++reg) {
                int gm = m0 + wm + i * 16 + quad * 4 + reg;
                int gn = n0 + wn + j * 16 + t16;
                out[(size_t)gm * EMBED + gn] = acc[i][j][reg];
            }
}

extern "C" void kernel_launch(void* const* d_in, const int* in_sizes, int n_in,
                              void* d_out, int out_size, void* d_ws, size_t ws_size,
                              hipStream_t stream) {
    const float* key   = (const float*)d_in[0];
    const float* query = (const float*)d_in[1];
    const float* value = (const float*)d_in[2];
    // d_in[3] = mask: causal tril, hardcoded
    const float* Wq = (const float*)d_in[4];
    const float* Wk = (const float*)d_in[5];
    const float* Wv = (const float*)d_in[6];
    const float* Wo = (const float*)d_in[7];

    char* ws = (char*)d_ws;
    _Float16* Ob   = (_Float16*)(ws);                // 16 MiB
    _Float16* Wq16 = (_Float16*)(ws + (16u << 20));  // 2 MiB each
    _Float16* Wk16 = (_Float16*)(ws + (18u << 20));
    _Float16* Wv16 = (_Float16*)(ws + (20u << 20));
    _Float16* Wo16 = (_Float16*)(ws + (22u << 20));
    _Float16* Qh   = (_Float16*)(ws + (24u << 20));  // 16 MiB [B,H,S,d]
    _Float16* Kh   = (_Float16*)(ws + (40u << 20));  // 16 MiB [B,H,S,d]
    _Float16* Vt   = (_Float16*)(ws + (56u << 20));  // 16 MiB, V fragment-major (see proj_qkv)

    dim3 blk(256);
    cvt_w<<<dim3(4096), blk, 0, stream>>>(Wq, Wk, Wv, Wo, Wq16, Wk16, Wv16, Wo16);
    proj_qkv<<<dim3(64, 8, 3), blk, 0, stream>>>(query, key, value, Wq16, Wk16, Wv16, Qh, Kh, Vt);
    attn3<<<dim3(64, 16), blk, 0, stream>>>(Qh, Kh, Vt, Ob);
    proj_out<<<dim3(64, 8), blk, 0, stream>>>(Ob, Wo16, (float*)d_out);
}